// Round 7
// baseline (2117.316 us; speedup 1.0000x reference)
//
#include <hip/hip_runtime.h>
#include <hip/hip_bf16.h>

typedef __hip_bfloat16 bf16;
typedef __attribute__((ext_vector_type(8))) short short8;
typedef __attribute__((ext_vector_type(4))) float floatx4;

__device__ __forceinline__ float b2f(bf16 v) { return __bfloat162float(v); }
__device__ __forceinline__ short f2bs(float v) {
    bf16 h = __float2bfloat16(v);
    return *(short*)&h;
}
__device__ __forceinline__ float invfreq(int jj) {
    return expf(-0.25584278811044955f * (float)jj);   // 10000^(-jj/36)
}

// MODE 0: input tensor is bf16.  MODE 1: input tensor is float32.
template<int MODE>
__device__ __forceinline__ float ldin(const void* p, long i) {
    if (MODE == 0) return b2f(((const bf16*)p)[i]);
    else           return ((const float*)p)[i];
}
__device__ __forceinline__ float ldf(const void* p, long i, int fl) {
    return fl == 0 ? b2f(((const bf16*)p)[i]) : ((const float*)p)[i];
}

#define SCALE_ 0.11785113019775793f   // 72^-0.5

// ---------------- dtype detector ----------------
__global__ void k_detect(const void* __restrict__ x, int* __restrict__ flag)
{
    const unsigned short* u = (const unsigned short*)x;
    int tid = threadIdx.x;
    int insane = 0;
    for (int i = tid; i < 2048; i += 64) {
        unsigned short s = u[i];
        int ex = (s >> 7) & 0xFF;
        if (ex >= 0xC5) insane++;
    }
    #pragma unroll
    for (int off = 32; off > 0; off >>= 1) insane += __shfl_down(insane, off);
    if (tid == 0) flag[0] = (insane > 8) ? 1 : 0;
}

// ---------------- merged setup: silu + c-cvt + bias cvts + rope ----------------
__global__ void k_setup(const void* __restrict__ c4t, const void* __restrict__ c,
                        const void* __restrict__ t_fcb, const void* __restrict__ mlp_b1,
                        const void* __restrict__ mlp_b2, const int* __restrict__ f,
                        float* __restrict__ sc4, float* __restrict__ cf32,
                        float* __restrict__ fcb_f, float* __restrict__ b1_f,
                        float* __restrict__ b2_f, float* __restrict__ ropeC,
                        float* __restrict__ ropeS, const int* __restrict__ flg)
{
    int i = blockIdx.x * 256 + threadIdx.x;
    int fl = *flg;
    if (i < 2304) {
        float v = ldf(c4t, i, fl);
        sc4[i] = v / (1.f + expf(-v));
    } else if (i < 39168) {
        cf32[i - 2304] = ldf(c, i - 2304, fl);
    } else if (i < 40320) {
        fcb_f[i - 39168] = ldf(t_fcb, i - 39168, fl);
    } else if (i < 44928) {
        b1_f[i - 40320] = ldf(mlp_b1, i - 40320, fl);
    } else if (i < 46080) {
        b2_f[i - 44928] = ldf(mlp_b2, i - 44928, fl);
    } else if (i < 47232) {
        int idx = i - 46080;
        int t = idx / 72, d = idx - t * 72;
        float ang = (float)f[t] * invfreq(d >> 1);
        float sn, cs; sincosf(ang, &sn, &cs);
        ropeC[idx] = cs;
        ropeS[idx] = sn;
    }
}

// ---------------- weight transpose+convert: W (KxN) -> Wt (NxK bf16) ----------------
template<int MODE>
__device__ __forceinline__ void wt_body(float (*tile)[33], const void* __restrict__ W,
    bf16* __restrict__ Wt, int K, int N)
{
    int n0 = blockIdx.x << 5, k0 = blockIdx.y << 5;
    int tid = threadIdx.x;
    int r = tid >> 3, c4 = (tid & 7) << 2;
    long base = (long)(k0 + r) * N + n0 + c4;
    #pragma unroll
    for (int i = 0; i < 4; ++i) tile[r][c4 + i] = ldin<MODE>(W, base + i);
    __syncthreads();
    long obase = (long)(n0 + r) * K + k0 + c4;
    #pragma unroll
    for (int i = 0; i < 4; ++i) Wt[obase + i] = __float2bfloat16(tile[c4 + i][r]);
}

__global__ __launch_bounds__(256) void k_wt(const void* __restrict__ W,
    bf16* __restrict__ Wt, int K, int N, const int* __restrict__ flg)
{
    __shared__ float tile[32][33];
    if (*flg == 0) wt_body<0>(tile, W, Wt, K, N);
    else           wt_body<1>(tile, W, Wt, K, N);
}

// batched: two K=1152,N=3456 transposes (t_qkv, s_qkv), outputs contiguous
__global__ __launch_bounds__(256) void k_wt2(const void* __restrict__ W0,
    const void* __restrict__ W1, bf16* __restrict__ Wt0, const int* __restrict__ flg)
{
    __shared__ float tile[32][33];
    const void* W = blockIdx.z ? W1 : W0;
    bf16* Wt = Wt0 + (long)blockIdx.z * 3981312;
    if (*flg == 0) wt_body<0>(tile, W, Wt, 1152, 3456);
    else           wt_body<1>(tile, W, Wt, 1152, 3456);
}

// batched: three 1152x1152 transposes (t_outw, t_fcw, s_outw), outputs contiguous
__global__ __launch_bounds__(256) void k_wt3(const void* __restrict__ W0,
    const void* __restrict__ W1, const void* __restrict__ W2,
    bf16* __restrict__ Wt0, const int* __restrict__ flg)
{
    __shared__ float tile[32][33];
    const void* W = (blockIdx.z == 0) ? W0 : (blockIdx.z == 1) ? W1 : W2;
    bf16* Wt = Wt0 + (long)blockIdx.z * 1327104;
    if (*flg == 0) wt_body<0>(tile, W, Wt, 1152, 1152);
    else           wt_body<1>(tile, W, Wt, 1152, 1152);
}

// ---------------- small f32 GEMM (ada + context projections) ----------------
// Cb non-null: write bf16 to Cb instead of f32 to C.
template<int MODE>
__device__ __forceinline__ void gemm_body(
    float (*As)[64], float (*Bs)[64],
    const float* __restrict__ A, const void* __restrict__ W,
    const void* __restrict__ bias, float* __restrict__ C,
    bf16* __restrict__ Cb, int row0, int R, int K, int N)
{
    int tid = threadIdx.x;
    int tx = tid & 15, ty = tid >> 4;
    int col0 = blockIdx.x << 6;
    float acc[4][4] = {};
    int ar = tid >> 2;
    int ak = (tid & 3) << 2;
    int bk = tid >> 4;
    int bc = (tid & 15) << 2;
    for (int kt = 0; kt < K; kt += 16) {
        if (row0 + ar < R) {
            const float4 a4 = *(const float4*)(A + (long)(row0 + ar) * K + kt + ak);
            As[ak + 0][ar] = a4.x; As[ak + 1][ar] = a4.y;
            As[ak + 2][ar] = a4.z; As[ak + 3][ar] = a4.w;
        } else {
            As[ak + 0][ar] = 0.f; As[ak + 1][ar] = 0.f;
            As[ak + 2][ar] = 0.f; As[ak + 3][ar] = 0.f;
        }
        #pragma unroll
        for (int i = 0; i < 4; ++i)
            Bs[bk][bc + i] = ldin<MODE>(W, (long)(kt + bk) * N + col0 + bc + i);
        __syncthreads();
        #pragma unroll
        for (int kk = 0; kk < 16; ++kk) {
            float4 av = *(const float4*)&As[kk][ty << 2];
            float4 bv = *(const float4*)&Bs[kk][tx << 2];
            float a[4] = {av.x, av.y, av.z, av.w};
            float b[4] = {bv.x, bv.y, bv.z, bv.w};
            #pragma unroll
            for (int i = 0; i < 4; ++i)
                #pragma unroll
                for (int j = 0; j < 4; ++j)
                    acc[i][j] += a[i] * b[j];
        }
        __syncthreads();
    }
    #pragma unroll
    for (int i = 0; i < 4; ++i) {
        int gr = row0 + (ty << 2) + i;
        if (gr >= R) continue;
        #pragma unroll
        for (int j = 0; j < 4; ++j) {
            float v = acc[i][j];
            int cc = col0 + (tx << 2) + j;
            if (bias) v += ldin<MODE>(bias, cc);
            if (Cb) Cb[(long)gr * N + cc] = __float2bfloat16(v);
            else    C[(long)gr * N + cc] = v;
        }
    }
}

__global__ __launch_bounds__(256) void k_gemm(
    const float* __restrict__ A, const void* __restrict__ W,
    const void* __restrict__ bias, float* __restrict__ C,
    int R, int K, int N, const int* __restrict__ flg)
{
    __shared__ float As[16][64];
    __shared__ float Bs[16][64];
    if (*flg == 0) gemm_body<0>(As, Bs, A, W, bias, C, nullptr, (int)(blockIdx.y << 6), R, K, N);
    else           gemm_body<1>(As, Bs, A, W, bias, C, nullptr, (int)(blockIdx.y << 6), R, K, N);
}

// batched context projections: y selects weight among {t_k,t_v,s_k,s_v};
// z=0,1 -> f32 outputs ekt,evt; z=2,3 -> bf16 outputs eksb,evsb (direct)
__global__ __launch_bounds__(256) void k_gemm4(
    const float* __restrict__ A, const void* __restrict__ W0,
    const void* __restrict__ W1, const void* __restrict__ W2,
    const void* __restrict__ W3, float* __restrict__ C0,
    bf16* __restrict__ Cb0, const int* __restrict__ flg)
{
    __shared__ float As[16][64];
    __shared__ float Bs[16][64];
    int z = blockIdx.y;
    const void* W = (z == 0) ? W0 : (z == 1) ? W1 : (z == 2) ? W2 : W3;
    float* C = C0 + (long)z * 36864;
    bf16* Cb = (z >= 2) ? Cb0 + (long)(z - 2) * 36864 : nullptr;
    if (*flg == 0) gemm_body<0>(As, Bs, A, W, nullptr, C, Cb, 0, 32, 1152, 1152);
    else           gemm_body<1>(As, Bs, A, W, nullptr, C, Cb, 0, 32, 1152, 1152);
}

// ---------------- MFMA GEMM: A(bf16 MxK) @ Wt(bf16 NxK)^T -> C ----------------
// Barrier-free, LDS-free register staging: each wave owns a 64x64 output
// sub-tile and loads its A/B fragments straight to VGPRs with plain
// global_load_dwordx4, register double-buffered (static indices). No
// s_barrier / GLDS / LDS hazards in the K-loop: waves free-run, compiler
// pipelines loads across iterations, TLP from 3 blocks/CU (0 LDS).
// Compile-time epilogue:
//   EMODE 0: C = v (bf16/f32 per outbf, optional fast gelu)
//   EMODE 1: x4[perm(row)] = x_in[perm(row)] + v  ((b,n,t)->(b,t,n) permute)
//   EMODE 2: x4[row] += ada_gate * v; optional final output write
template<int EMODE>
__global__ __launch_bounds__(256, 3) void k_mgemm(
    const bf16* __restrict__ A, const bf16* __restrict__ Wt,
    const float* __restrict__ bias, void* __restrict__ Cout,
    int K, int N, int outbf, int act,
    float* __restrict__ x4, const float* __restrict__ ada, int part,
    const void* __restrict__ xin, void* __restrict__ outp,
    const int* __restrict__ flg)
{
    int tid = threadIdx.x;
    int lane = tid & 63, wave = tid >> 6;   // 4 waves
    int mq = wave >> 1, nq = wave & 1;      // 2M x 2N wave grid

    // bijective XCD-chunked swizzle
    int gx = gridDim.x;
    int nwg = gx * (int)gridDim.y;
    int orig = blockIdx.y * gx + blockIdx.x;
    int qq = nwg >> 3, rr = nwg & 7;
    int xcd = orig & 7, loc = orig >> 3;
    int wg = (xcd < rr ? xcd * (qq + 1) : rr * (qq + 1) + (xcd - rr) * qq) + loc;
    int bx = wg % gx, by = wg / gx;

    long row0 = (long)by << 7;   // 128-row tile
    long col0 = (long)bx << 7;   // 128-col tile
    int mi = lane & 15, q = lane >> 4;

    // per-wave fragment pointers (row = base + group*16 + mi, k-offset q*8)
    const bf16* pa0 = A  + (row0 + mq * 64 + mi) * (long)K + q * 8;
    const bf16* pa1 = pa0 + 16 * (long)K;
    const bf16* pa2 = pa0 + 32 * (long)K;
    const bf16* pa3 = pa0 + 48 * (long)K;
    const bf16* pb0 = Wt + (col0 + nq * 64 + mi) * (long)K + q * 8;
    const bf16* pb1 = pb0 + 16 * (long)K;
    const bf16* pb2 = pb0 + 32 * (long)K;
    const bf16* pb3 = pb0 + 48 * (long)K;

    floatx4 acc[4][4] = {};
    int nt = K >> 5;             // K/32: 36 or 144 (even)

    short8 a0[4], b0[4], a1[4], b1[4];

#define LD8(dA, dB, kt) do { \
        dA[0] = *(const short8*)(pa0 + (kt)); \
        dA[1] = *(const short8*)(pa1 + (kt)); \
        dA[2] = *(const short8*)(pa2 + (kt)); \
        dA[3] = *(const short8*)(pa3 + (kt)); \
        dB[0] = *(const short8*)(pb0 + (kt)); \
        dB[1] = *(const short8*)(pb1 + (kt)); \
        dB[2] = *(const short8*)(pb2 + (kt)); \
        dB[3] = *(const short8*)(pb3 + (kt)); } while (0)

#define MM16(sA, sB) do { \
        _Pragma("unroll") \
        for (int i_ = 0; i_ < 4; ++i_) \
            _Pragma("unroll") \
            for (int j_ = 0; j_ < 4; ++j_) \
                acc[i_][j_] = __builtin_amdgcn_mfma_f32_16x16x32_bf16( \
                    sA[i_], sB[j_], acc[i_][j_], 0, 0, 0); } while (0)

    LD8(a0, b0, 0);
    for (int t = 0; t < nt; t += 2) {
        if (t + 1 < nt) LD8(a1, b1, (t + 1) * 32);
        MM16(a0, b0);
        if (t + 2 < nt) LD8(a0, b0, (t + 2) * 32);
        if (t + 1 < nt) MM16(a1, b1);
    }
#undef LD8
#undef MM16

    int lr = lane >> 4, lc = lane & 15;
    int fl = flg ? *flg : 0;
    float b4[4] = {0.f, 0.f, 0.f, 0.f};
    if (bias) {
        #pragma unroll
        for (int j = 0; j < 4; ++j) b4[j] = bias[(int)col0 + nq * 64 + j * 16 + lc];
    }
    #pragma unroll
    for (int i = 0; i < 4; ++i) {
        #pragma unroll
        for (int r = 0; r < 4; ++r) {
            long grow = row0 + mq * 64 + i * 16 + lr * 4 + r;
            #pragma unroll
            for (int j = 0; j < 4; ++j) {
                int col = (int)col0 + nq * 64 + j * 16 + lc;
                float v = acc[i][j][r] + b4[j];
                if (act) {
                    // gelu(tanh) == x * sigmoid(2 * 0.7978845608 * (x + 0.044715 x^3))
                    float u = v;
                    float tt = 1.5957691216057308f * (u + 0.044715f * u * u * u);
                    v = u / (1.f + __expf(-tt));
                }
                if constexpr (EMODE == 0) {
                    if (outbf) ((bf16*)Cout)[grow * N + col] = __float2bfloat16(v);
                    else       ((float*)Cout)[grow * N + col] = v;
                } else if constexpr (EMODE == 1) {
                    // grow is (b,n,t); x4/x rows are (b,t,n)
                    int bb = (int)(grow >> 12);
                    int nn = ((int)grow >> 4) & 255;
                    int tt2 = (int)grow & 15;
                    long rx = ((long)((bb << 4) + tt2) << 8) + nn;
                    long idx = rx * 1152 + col;
                    float xv = (fl == 0) ? b2f(((const bf16*)xin)[idx])
                                         : ((const float*)xin)[idx];
                    x4[idx] = xv + v;
                } else {
                    int bb = (int)(grow >> 12);
                    float g = ada[(bb * 6 + part) * 1152 + col];
                    long idx = grow * 1152 + col;
                    float nv = x4[idx] + g * v;
                    x4[idx] = nv;
                    if (outp) {
                        if (fl == 0) ((bf16*)outp)[idx] = __float2bfloat16(nv);
                        else         ((float*)outp)[idx] = nv;
                    }
                }
            }
        }
    }
}

// ---------------- LN (temporal) ----------------
template<int MODE>
__device__ __forceinline__ void ln_t_body(float* rs, float* rss,
    const void* __restrict__ x, const void* __restrict__ w,
    const void* __restrict__ bb, bf16* __restrict__ out)
{
    int r = blockIdx.x;
    int n = r & 255;
    int bt = r >> 8;
    int b = bt >> 4, t = bt & 15;
    long orow = (long)((b << 8) + n) * 16 + t;
    int tid = threadIdx.x;
    float vals[5];
    float s = 0.f, ss = 0.f;
    int c = 0;
    for (int i = tid; i < 1152; i += 256, ++c) {
        float v = ldin<MODE>(x, (long)r * 1152 + i);
        vals[c] = v; s += v; ss += v * v;
    }
    #pragma unroll
    for (int off = 32; off > 0; off >>= 1) {
        s  += __shfl_down(s, off);
        ss += __shfl_down(ss, off);
    }
    int wid = tid >> 6;
    if ((tid & 63) == 0) { rs[wid] = s; rss[wid] = ss; }
    __syncthreads();
    float S  = rs[0] + rs[1] + rs[2] + rs[3];
    float SS = rss[0] + rss[1] + rss[2] + rss[3];
    float mu = S * (1.f / 1152.f);
    float var = SS * (1.f / 1152.f) - mu * mu;
    float rstd = rsqrtf(var + 1e-5f);
    c = 0;
    bf16* op = out + orow * 1152;
    for (int i = tid; i < 1152; i += 256, ++c)
        op[i] = __float2bfloat16((vals[c] - mu) * rstd * ldin<MODE>(w, i) + ldin<MODE>(bb, i));
}

__global__ __launch_bounds__(256) void k_ln_t(
    const void* __restrict__ x, const void* __restrict__ w,
    const void* __restrict__ bb, bf16* __restrict__ out,
    const int* __restrict__ flg)
{
    __shared__ float rs[4], rss[4];
    if (*flg == 0) ln_t_body<0>(rs, rss, x, w, bb, out);
    else           ln_t_body<1>(rs, rss, x, w, bb, out);
}

// ---------------- LN + adaLN modulation ----------------
__global__ __launch_bounds__(256) void k_ln_mod(
    const float* __restrict__ x4, const float* __restrict__ ada,
    int psh, int psc, float eps, bf16* __restrict__ out)
{
    int r = blockIdx.x;
    int b = r >> 12;
    const float* xp = x4 + (long)r * 1152;
    int tid = threadIdx.x;
    float vals[5];
    float s = 0.f, ss = 0.f;
    int c = 0;
    for (int i = tid; i < 1152; i += 256, ++c) {
        float v = xp[i];
        vals[c] = v; s += v; ss += v * v;
    }
    #pragma unroll
    for (int off = 32; off > 0; off >>= 1) {
        s  += __shfl_down(s, off);
        ss += __shfl_down(ss, off);
    }
    __shared__ float rs[4], rss[4];
    int wid = tid >> 6;
    if ((tid & 63) == 0) { rs[wid] = s; rss[wid] = ss; }
    __syncthreads();
    float S  = rs[0] + rs[1] + rs[2] + rs[3];
    float SS = rss[0] + rss[1] + rss[2] + rss[3];
    float mu = S * (1.f / 1152.f);
    float var = SS * (1.f / 1152.f) - mu * mu;
    float rstd = rsqrtf(var + eps);
    const float* sh = ada + (b * 6 + psh) * 1152;
    const float* sc = ada + (b * 6 + psc) * 1152;
    c = 0;
    bf16* op = out + (long)r * 1152;
    for (int i = tid; i < 1152; i += 256, ++c)
        op[i] = __float2bfloat16((vals[c] - mu) * rstd * (1.f + sc[i]) + sh[i]);
}

// ---------------- temporal attention (conflict-free VALU) ----------------
__global__ __launch_bounds__(256) void k_attn_t(
    const bf16* __restrict__ qkv, const float* __restrict__ ekt,
    const float* __restrict__ evt, const float* __restrict__ ropeC,
    const float* __restrict__ ropeS, bf16* __restrict__ out)
{
    __shared__ float qs[16][73];
    __shared__ float ksT[72][33];
    __shared__ float vs[32][73];
    __shared__ float sc[16][33];
    int blk = blockIdx.x;
    int h = blk & 15;
    int bn = blk >> 4;
    int b = bn >> 8;
    int tid = threadIdx.x;
    long qbase = (long)bn * 16 * 3456 + h * 72;
    for (int idx = tid; idx < 16 * 72; idx += 256) {
        int i = idx / 72, d = idx - i * 72;
        long p0 = qbase + (long)i * 3456;
        float v  = b2f(qkv[p0 + d]);
        float v2 = b2f(qkv[p0 + (d ^ 1)]);
        float cs = ropeC[idx], sn = ropeS[idx];
        float rv = (d & 1) ? (v * cs + v2 * sn) : (v * cs - v2 * sn);
        qs[i][d] = rv * SCALE_;
    }
    for (int idx = tid; idx < 32 * 72; idx += 256) {
        int j = idx / 72, d = idx - j * 72;
        float kv, kv2, vv; int pi;
        if (j < 16) {
            long base = (long)(b * 16 + j) * 1152 + h * 72;
            kv  = ekt[base + d];
            kv2 = ekt[base + (d ^ 1)];
            vv  = evt[base + d];
            pi = j;
        } else {
            int jj = j - 16;
            long base = qbase + (long)jj * 3456;
            kv  = b2f(qkv[base + 1152 + d]);
            kv2 = b2f(qkv[base + 1152 + (d ^ 1)]);
            vv  = b2f(qkv[base + 2304 + d]);
            pi = jj;
        }
        float cs = ropeC[pi * 72 + d], sn = ropeS[pi * 72 + d];
        ksT[d][j] = (d & 1) ? (kv * cs + kv2 * sn) : (kv * cs - kv2 * sn);
        vs[j][d] = vv;
    }
    __syncthreads();
    for (int e = tid; e < 512; e += 256) {
        int i = e >> 5, j = e & 31;
        float s = 0.f;
        for (int d = 0; d < 72; ++d) s += qs[i][d] * ksT[d][j];
        sc[i][j] = s;
    }
    __syncthreads();
    if (tid < 16) {
        float m = -1e30f;
        for (int j = 0; j < 32; ++j) m = fmaxf(m, sc[tid][j]);
        float l = 0.f;
        for (int j = 0; j < 32; ++j) { float p = expf(sc[tid][j] - m); sc[tid][j] = p; l += p; }
        float inv = 1.f / l;
        for (int j = 0; j < 32; ++j) sc[tid][j] *= inv;
    }
    __syncthreads();
    for (int idx = tid; idx < 16 * 72; idx += 256) {
        int i = idx / 72, d = idx - i * 72;
        float o = 0.f;
        for (int j = 0; j < 32; ++j) o += sc[i][j] * vs[j][d];
        out[((long)bn * 16 + i) * 1152 + h * 72 + d] = __float2bfloat16(o);
    }
}

// ---------------- spatial attention: MFMA flash ----------------
__global__ __launch_bounds__(256) void k_attn_s(
    const bf16* __restrict__ qkv, const bf16* __restrict__ eksb,
    const bf16* __restrict__ evsb, bf16* __restrict__ out)
{
    __shared__ short vT[5120];       // V^T frag-linear: (dn*2+ks)*512 + fl*8
    __shared__ short pl[4][1024];    // per-wave P frags: ks*512 + lane*8
    int tid = threadIdx.x;
    int lane = tid & 63, wave = tid >> 6;
    int blk = blockIdx.x;
    int ic = blk & 3;
    int bth = blk >> 2;
    int h = bth & 15;
    int bt = bth >> 4;
    int col = lane & 15, q = lane >> 4;
    int hoff = h * 72;
    long qkvbase = (long)bt * 256 * 3456;
    long ctxbase = (long)bt * 1152 + hoff;

    int qrow = ic * 64 + wave * 16 + col;
    const bf16* qptr = qkv + qkvbase + (long)qrow * 3456 + hoff;
    short8 qf[3];
    #pragma unroll
    for (int ks = 0; ks < 3; ++ks) {
        int k0 = ks * 32 + q * 8;
        if (k0 + 8 <= 72) qf[ks] = *(const short8*)(qptr + k0);
        else { short8 z = {0,0,0,0,0,0,0,0}; qf[ks] = z; }
    }

    floatx4 o[5] = {};
    float m_i[4], l_i[4];
    #pragma unroll
    for (int r = 0; r < 4; ++r) { m_i[r] = -1e30f; l_i[r] = 0.f; }

    for (int kc = 0; kc < 320; kc += 64) {
        for (int fi = tid; fi < 640; fi += 256) {
            int blkid = fi >> 6, fl2 = fi & 63;
            int dn = blkid >> 1, ks = blkid & 1;
            int d = dn * 16 + (fl2 & 15);
            int kq = fl2 >> 4;
            short8 v;
            #pragma unroll
            for (int j = 0; j < 8; ++j) {
                int gk = kc + ks * 32 + kq * 8 + j;
                short sv = 0;
                if (d < 72 && gk <= 256) {
                    if (gk == 0) sv = *(const short*)(eksb ? &evsb[ctxbase + d] : nullptr);
                    else sv = *(const short*)&qkv[qkvbase + (long)(gk - 1) * 3456 + 2304 + hoff + d];
                }
                v[j] = sv;
            }
            *(short8*)&vT[blkid * 512 + fl2 * 8] = v;
        }
        __syncthreads();

        floatx4 sacc[4] = {};
        #pragma unroll
        for (int nt = 0; nt < 4; ++nt) {
            int key = kc + nt * 16 + col;
            #pragma unroll
            for (int ks = 0; ks < 3; ++ks) {
                int k0 = ks * 32 + q * 8;
                short8 kf = {0,0,0,0,0,0,0,0};
                if (key <= 256 && k0 + 8 <= 72) {
                    if (key == 0) kf = *(const short8*)(eksb + ctxbase + k0);
                    else kf = *(const short8*)(qkv + qkvbase + (long)(key - 1) * 3456 + 1152 + hoff + k0);
                }
                sacc[nt] = __builtin_amdgcn_mfma_f32_16x16x32_bf16(qf[ks], kf, sacc[nt], 0, 0, 0);
            }
        }

        float p[4][4];
        #pragma unroll
        for (int r = 0; r < 4; ++r) {
            float mv = -1e30f;
            #pragma unroll
            for (int nt = 0; nt < 4; ++nt) {
                int key = kc + nt * 16 + col;
                float s = (key <= 256) ? sacc[nt][r] * SCALE_ : -1e30f;
                p[nt][r] = s;
                mv = fmaxf(mv, s);
            }
            #pragma unroll
            for (int xm = 1; xm < 16; xm <<= 1) mv = fmaxf(mv, __shfl_xor(mv, xm));
            float mn = fmaxf(m_i[r], mv);
            float alpha = expf(m_i[r] - mn);
            m_i[r] = mn;
            float rsum = 0.f;
            #pragma unroll
            for (int nt = 0; nt < 4; ++nt) {
                float e = expf(p[nt][r] - mn);
                p[nt][r] = e;
                rsum += e;
            }
            #pragma unroll
            for (int xm = 1; xm < 16; xm <<= 1) rsum += __shfl_xor(rsum, xm);
            l_i[r] = l_i[r] * alpha + rsum;
            #pragma unroll
            for (int dn = 0; dn < 5; ++dn) o[dn][r] *= alpha;
        }

        #pragma unroll
        for (int nt = 0; nt < 4; ++nt) {
            int kl = nt * 16 + col;
            int ks2 = kl >> 5, q2 = (kl >> 3) & 3, j = kl & 7;
            #pragma unroll
            for (int r = 0; r < 4; ++r) {
                int mrow = q * 4 + r;
                pl[wave][ks2 * 512 + q2 * 128 + mrow * 8 + j] = f2bs(p[nt][r]);
            }
        }
        __syncthreads();

        #pragma unroll
        for (int ks = 0; ks < 2; ++ks) {
            short8 pf = *(const short8*)&pl[wave][ks * 512 + lane * 8];
            #pragma unroll
            for (int dn = 0; dn < 5; ++dn) {
                short8 vf = *(const short8*)&vT[(dn * 2 + ks) * 512 + lane * 8];
                o[dn] = __builtin_amdgcn_mfma_f32_16x16x32_bf16(pf, vf, o[dn], 0, 0, 0);
            }
        }
        __syncthreads();
    }

    int orow0 = ic * 64 + wave * 16;
    #pragma unroll
    for (int dn = 0; dn < 5; ++dn) {
        int d = dn * 16 + col;
        if (d >= 72) continue;
        #pragma unroll
        for (int r = 0; r < 4; ++r) {
            int mrow = q * 4 + r;
            float val = o[dn][r] / l_i[r];
            out[((long)bt * 256 + orow0 + mrow) * 1152 + hoff + d] = __float2bfloat16(val);
        }
    }
}

extern "C" void kernel_launch(void* const* d_in, const int* in_sizes, int n_in,
                              void* d_out, int out_size, void* d_ws, size_t ws_size,
                              hipStream_t stream)
{
    const void* x      = d_in[0];
    const void* c4t    = d_in[1];
    const void* c      = d_in[2];
    const void* W_ada  = d_in[3];
    const void* b_ada  = d_in[4];
    const void* tn_w   = d_in[5];
    const void* tn_b   = d_in[6];
    const void* t_qkv  = d_in[7];
    const void* t_k    = d_in[8];
    const void* t_v    = d_in[9];
    const void* t_outw = d_in[10];
    const void* t_fcw  = d_in[11];
    const void* t_fcb  = d_in[12];
    const void* s_qkv  = d_in[13];
    const void* s_k    = d_in[14];
    const void* s_v    = d_in[15];
    const void* s_outw = d_in[16];
    const void* mlp_w1 = d_in[17];
    const void* mlp_b1 = d_in[18];
    const void* mlp_w2 = d_in[19];
    const void* mlp_b2 = d_in[20];
    const int*  f      = (const int*)d_in[21];

    float* ws    = (float*)d_ws;
    float* x4    = ws;                        //  9,437,184 f32
    float* buf2  = x4 + 9437184;              //  9,437,184 f32
    float* reg1f = buf2 + 9437184;            // 18,874,368 f32-slots
    bf16*  qkvb  = (bf16*)reg1f;
    bf16*  hbf   = (bf16*)reg1f;
    float* abfAf = reg1f + 18874368;          //  4,718,592 f32-slots
    bf16*  abfA  = (bf16*)abfAf;
    float* abfBf = abfAf + 4718592;           //  4,718,592 f32-slots
    bf16*  abfB  = (bf16*)abfBf;
    float* wtf   = abfBf + 4718592;           // 11,280,384 f32-slots
    bf16*  wt    = (bf16*)wtf;
    bf16* t_qkv_t = wt;
    bf16* s_qkv_t = t_qkv_t + 3981312;
    bf16* t_out_t = s_qkv_t + 3981312;
    bf16* t_fc_t  = t_out_t + 1327104;
    bf16* s_out_t = t_fc_t  + 1327104;
    bf16* w1_t    = s_out_t + 1327104;
    bf16* w2_t    = w1_t    + 5308416;
    float* small  = wtf + 11280384;
    float* ada   = small;                      // 13,824
    float* cf32  = ada  + 13824;               // 36,864
    float* ekt   = cf32 + 36864;
    float* evt   = ekt  + 36864;
    float* eks   = evt  + 36864;
    float* evs   = eks  + 36864;
    bf16*  eksb  = (bf16*)(evs + 36864);       // 36,864 bf16 -> 18,432 f32 slots
    bf16*  evsb  = eksb + 36864;               // 36,864 bf16
    float* sc4   = (float*)(evsb + 36864);     // 2,304
    float* fcb_f = sc4  + 2304;
    float* b1_f  = fcb_f + 1152;
    float* b2_f  = b1_f  + 4608;
    float* ropeC = b2_f + 1152;
    float* ropeS = ropeC + 1152;
    int*   flg   = (int*)(ropeS + 1152);

    k_detect<<<1, 64, 0, stream>>>(x, flg);
    k_setup<<<185, 256, 0, stream>>>(c4t, c, t_fcb, mlp_b1, mlp_b2, f,
                                     sc4, cf32, fcb_f, b1_f, b2_f, ropeC, ropeS, flg);

    // ---- modulation + context projections (z>=2 write bf16 directly) ----
    k_gemm<<<dim3(108, 1), 256, 0, stream>>>(sc4, W_ada, b_ada, ada, 2, 1152, 6912, flg);
    k_gemm4<<<dim3(18, 4), 256, 0, stream>>>(cf32, t_k, t_v, s_k, s_v, ekt, eksb, flg);

    // ---- weight transpose+convert ----
    k_wt2<<<dim3(108, 36, 2), 256, 0, stream>>>(t_qkv, s_qkv, t_qkv_t, flg);
    k_wt3<<<dim3(36, 36, 3), 256, 0, stream>>>(t_outw, t_fcw, s_outw, t_out_t, flg);
    k_wt<<<dim3(144, 36), 256, 0, stream>>>(mlp_w1, w1_t, 1152, 4608, flg);
    k_wt<<<dim3(36, 144), 256, 0, stream>>>(mlp_w2, w2_t, 4608, 1152, flg);

    // ---- temporal attention ----
    k_ln_t<<<8192, 256, 0, stream>>>(x, tn_w, tn_b, abfA, flg);
    k_mgemm<0><<<dim3(27, 64), 256, 0, stream>>>(abfA, t_qkv_t, nullptr, qkvb, 1152, 3456, 1, 0,
                                                 nullptr, nullptr, 0, nullptr, nullptr, flg);
    k_attn_t<<<8192, 256, 0, stream>>>(qkvb, ekt, evt, ropeC, ropeS, abfB);
    k_mgemm<0><<<dim3(9, 64), 256, 0, stream>>>(abfB, t_out_t, nullptr, abfA, 1152, 1152, 1, 0,
                                                nullptr, nullptr, 0, nullptr, nullptr, flg);
    // t_fc fused with residual add + (b,n,t)->(b,t,n) permute
    k_mgemm<1><<<dim3(9, 64), 256, 0, stream>>>(abfA, t_fc_t, fcb_f, nullptr, 1152, 1152, 0, 0,
                                                x4, nullptr, 0, x, nullptr, flg);

    // ---- spatial attention ----
    k_ln_mod<<<8192, 256, 0, stream>>>(x4, ada, 0, 1, 1e-6f, abfA);
    k_mgemm<0><<<dim3(27, 64), 256, 0, stream>>>(abfA, s_qkv_t, nullptr, qkvb, 1152, 3456, 1, 0,
                                                 nullptr, nullptr, 0, nullptr, nullptr, flg);
    k_attn_s<<<2048, 256, 0, stream>>>(qkvb, eksb, evsb, abfB);
    // s_out fused with gated accumulate (part 2)
    k_mgemm<2><<<dim3(9, 64), 256, 0, stream>>>(abfB, s_out_t, nullptr, nullptr, 1152, 1152, 0, 0,
                                                x4, ada, 2, nullptr, nullptr, flg);

    // ---- MLP ----
    k_ln_mod<<<8192, 256, 0, stream>>>(x4, ada, 3, 4, 1e-6f, abfA);
    k_mgemm<0><<<dim3(36, 64), 256, 0, stream>>>(abfA, w1_t, b1_f, hbf, 1152, 4608, 1, 1,
                                                 nullptr, nullptr, 0, nullptr, nullptr, flg);
    // w2 fused with gated accumulate (part 5) + final output emit
    k_mgemm<2><<<dim3(9, 64), 256, 0, stream>>>(hbf, w2_t, b2_f, nullptr, 4608, 1152, 0, 0,
                                                x4, ada, 5, nullptr, d_out, flg);
}

// Round 8
// 1462.129 us; speedup vs baseline: 1.4481x; 1.4481x over previous
//
#include <hip/hip_runtime.h>
#include <hip/hip_bf16.h>

typedef __hip_bfloat16 bf16;
typedef __attribute__((ext_vector_type(8))) short short8;
typedef __attribute__((ext_vector_type(4))) float floatx4;

__device__ __forceinline__ float b2f(bf16 v) { return __bfloat162float(v); }
__device__ __forceinline__ short f2bs(float v) {
    bf16 h = __float2bfloat16(v);
    return *(short*)&h;
}
__device__ __forceinline__ float invfreq(int jj) {
    return expf(-0.25584278811044955f * (float)jj);   // 10000^(-jj/36)
}

// MODE 0: input tensor is bf16.  MODE 1: input tensor is float32.
template<int MODE>
__device__ __forceinline__ float ldin(const void* p, long i) {
    if (MODE == 0) return b2f(((const bf16*)p)[i]);
    else           return ((const float*)p)[i];
}
__device__ __forceinline__ float ldf(const void* p, long i, int fl) {
    return fl == 0 ? b2f(((const bf16*)p)[i]) : ((const float*)p)[i];
}

#define SCALE_ 0.11785113019775793f   // 72^-0.5

// async global->LDS, 16B per lane
#define GLDS(gp, lp) __builtin_amdgcn_global_load_lds( \
    (const __attribute__((address_space(1))) void*)(gp), \
    (__attribute__((address_space(3))) void*)(lp), 16, 0, 0)

// ---------------- dtype detector ----------------
__global__ void k_detect(const void* __restrict__ x, int* __restrict__ flag)
{
    const unsigned short* u = (const unsigned short*)x;
    int tid = threadIdx.x;
    int insane = 0;
    for (int i = tid; i < 2048; i += 64) {
        unsigned short s = u[i];
        int ex = (s >> 7) & 0xFF;
        if (ex >= 0xC5) insane++;
    }
    #pragma unroll
    for (int off = 32; off > 0; off >>= 1) insane += __shfl_down(insane, off);
    if (tid == 0) flag[0] = (insane > 8) ? 1 : 0;
}

// ---------------- merged setup: silu + c-cvt + bias cvts + rope ----------------
__global__ void k_setup(const void* __restrict__ c4t, const void* __restrict__ c,
                        const void* __restrict__ t_fcb, const void* __restrict__ mlp_b1,
                        const void* __restrict__ mlp_b2, const int* __restrict__ f,
                        float* __restrict__ sc4, float* __restrict__ cf32,
                        float* __restrict__ fcb_f, float* __restrict__ b1_f,
                        float* __restrict__ b2_f, float* __restrict__ ropeC,
                        float* __restrict__ ropeS, const int* __restrict__ flg)
{
    int i = blockIdx.x * 256 + threadIdx.x;
    int fl = *flg;
    if (i < 2304) {
        float v = ldf(c4t, i, fl);
        sc4[i] = v / (1.f + expf(-v));
    } else if (i < 39168) {
        cf32[i - 2304] = ldf(c, i - 2304, fl);
    } else if (i < 40320) {
        fcb_f[i - 39168] = ldf(t_fcb, i - 39168, fl);
    } else if (i < 44928) {
        b1_f[i - 40320] = ldf(mlp_b1, i - 40320, fl);
    } else if (i < 46080) {
        b2_f[i - 44928] = ldf(mlp_b2, i - 44928, fl);
    } else if (i < 47232) {
        int idx = i - 46080;
        int t = idx / 72, d = idx - t * 72;
        float ang = (float)f[t] * invfreq(d >> 1);
        float sn, cs; sincosf(ang, &sn, &cs);
        ropeC[idx] = cs;
        ropeS[idx] = sn;
    }
}

// ---------------- flagged -> bf16 straight convert ----------------
__global__ void k_cvtf(const void* __restrict__ in, bf16* __restrict__ out, int n,
                       const int* __restrict__ flg)
{
    int i = blockIdx.x * 256 + threadIdx.x;
    if (i < n) out[i] = __float2bfloat16(ldf(in, i, *flg));
}

// ---------------- weight transpose+convert: W (KxN) -> Wt (NxK bf16) ----------------
template<int MODE>
__device__ __forceinline__ void wt_body(float (*tile)[33], const void* __restrict__ W,
    bf16* __restrict__ Wt, int K, int N)
{
    int n0 = blockIdx.x << 5, k0 = blockIdx.y << 5;
    int tid = threadIdx.x;
    int r = tid >> 3, c4 = (tid & 7) << 2;
    long base = (long)(k0 + r) * N + n0 + c4;
    #pragma unroll
    for (int i = 0; i < 4; ++i) tile[r][c4 + i] = ldin<MODE>(W, base + i);
    __syncthreads();
    long obase = (long)(n0 + r) * K + k0 + c4;
    #pragma unroll
    for (int i = 0; i < 4; ++i) Wt[obase + i] = __float2bfloat16(tile[c4 + i][r]);
}

__global__ __launch_bounds__(256) void k_wt(const void* __restrict__ W,
    bf16* __restrict__ Wt, int K, int N, const int* __restrict__ flg)
{
    __shared__ float tile[32][33];
    if (*flg == 0) wt_body<0>(tile, W, Wt, K, N);
    else           wt_body<1>(tile, W, Wt, K, N);
}

// batched: two K=1152,N=3456 transposes (t_qkv, s_qkv), outputs contiguous
__global__ __launch_bounds__(256) void k_wt2(const void* __restrict__ W0,
    const void* __restrict__ W1, bf16* __restrict__ Wt0, const int* __restrict__ flg)
{
    __shared__ float tile[32][33];
    const void* W = blockIdx.z ? W1 : W0;
    bf16* Wt = Wt0 + (long)blockIdx.z * 3981312;
    if (*flg == 0) wt_body<0>(tile, W, Wt, 1152, 3456);
    else           wt_body<1>(tile, W, Wt, 1152, 3456);
}

// batched: three 1152x1152 transposes (t_outw, t_fcw, s_outw), outputs contiguous
__global__ __launch_bounds__(256) void k_wt3(const void* __restrict__ W0,
    const void* __restrict__ W1, const void* __restrict__ W2,
    bf16* __restrict__ Wt0, const int* __restrict__ flg)
{
    __shared__ float tile[32][33];
    const void* W = (blockIdx.z == 0) ? W0 : (blockIdx.z == 1) ? W1 : W2;
    bf16* Wt = Wt0 + (long)blockIdx.z * 1327104;
    if (*flg == 0) wt_body<0>(tile, W, Wt, 1152, 1152);
    else           wt_body<1>(tile, W, Wt, 1152, 1152);
}

// ---------------- small f32 GEMM (ada + context projections) ----------------
// Cb non-null: write bf16 to Cb instead of f32 to C.
template<int MODE>
__device__ __forceinline__ void gemm_body(
    float (*As)[64], float (*Bs)[64],
    const float* __restrict__ A, const void* __restrict__ W,
    const void* __restrict__ bias, float* __restrict__ C,
    bf16* __restrict__ Cb, int row0, int R, int K, int N)
{
    int tid = threadIdx.x;
    int tx = tid & 15, ty = tid >> 4;
    int col0 = blockIdx.x << 6;
    float acc[4][4] = {};
    int ar = tid >> 2;
    int ak = (tid & 3) << 2;
    int bk = tid >> 4;
    int bc = (tid & 15) << 2;
    for (int kt = 0; kt < K; kt += 16) {
        if (row0 + ar < R) {
            const float4 a4 = *(const float4*)(A + (long)(row0 + ar) * K + kt + ak);
            As[ak + 0][ar] = a4.x; As[ak + 1][ar] = a4.y;
            As[ak + 2][ar] = a4.z; As[ak + 3][ar] = a4.w;
        } else {
            As[ak + 0][ar] = 0.f; As[ak + 1][ar] = 0.f;
            As[ak + 2][ar] = 0.f; As[ak + 3][ar] = 0.f;
        }
        #pragma unroll
        for (int i = 0; i < 4; ++i)
            Bs[bk][bc + i] = ldin<MODE>(W, (long)(kt + bk) * N + col0 + bc + i);
        __syncthreads();
        #pragma unroll
        for (int kk = 0; kk < 16; ++kk) {
            float4 av = *(const float4*)&As[kk][ty << 2];
            float4 bv = *(const float4*)&Bs[kk][tx << 2];
            float a[4] = {av.x, av.y, av.z, av.w};
            float b[4] = {bv.x, bv.y, bv.z, bv.w};
            #pragma unroll
            for (int i = 0; i < 4; ++i)
                #pragma unroll
                for (int j = 0; j < 4; ++j)
                    acc[i][j] += a[i] * b[j];
        }
        __syncthreads();
    }
    #pragma unroll
    for (int i = 0; i < 4; ++i) {
        int gr = row0 + (ty << 2) + i;
        if (gr >= R) continue;
        #pragma unroll
        for (int j = 0; j < 4; ++j) {
            float v = acc[i][j];
            int cc = col0 + (tx << 2) + j;
            if (bias) v += ldin<MODE>(bias, cc);
            if (Cb) Cb[(long)gr * N + cc] = __float2bfloat16(v);
            else    C[(long)gr * N + cc] = v;
        }
    }
}

__global__ __launch_bounds__(256) void k_gemm(
    const float* __restrict__ A, const void* __restrict__ W,
    const void* __restrict__ bias, float* __restrict__ C,
    int R, int K, int N, const int* __restrict__ flg)
{
    __shared__ float As[16][64];
    __shared__ float Bs[16][64];
    if (*flg == 0) gemm_body<0>(As, Bs, A, W, bias, C, nullptr, (int)(blockIdx.y << 6), R, K, N);
    else           gemm_body<1>(As, Bs, A, W, bias, C, nullptr, (int)(blockIdx.y << 6), R, K, N);
}

// batched context projections: y selects weight among {t_k,t_v,s_k,s_v};
// z=0,1 -> f32 outputs ekt,evt; z=2,3 -> bf16 outputs eksb,evsb (direct)
__global__ __launch_bounds__(256) void k_gemm4(
    const float* __restrict__ A, const void* __restrict__ W0,
    const void* __restrict__ W1, const void* __restrict__ W2,
    const void* __restrict__ W3, float* __restrict__ C0,
    bf16* __restrict__ Cb0, const int* __restrict__ flg)
{
    __shared__ float As[16][64];
    __shared__ float Bs[16][64];
    int z = blockIdx.y;
    const void* W = (z == 0) ? W0 : (z == 1) ? W1 : (z == 2) ? W2 : W3;
    float* C = C0 + (long)z * 36864;
    bf16* Cb = (z >= 2) ? Cb0 + (long)(z - 2) * 36864 : nullptr;
    if (*flg == 0) gemm_body<0>(As, Bs, A, W, nullptr, C, Cb, 0, 32, 1152, 1152);
    else           gemm_body<1>(As, Bs, A, W, nullptr, C, Cb, 0, 32, 1152, 1152);
}

// ---------------- MFMA GEMM: A(bf16 MxK) @ Wt(bf16 NxK)^T -> C ----------------
// (Round-6 proven version.) 128x128 tile, 4 waves (2Mx2N), BK=32, 3-stage LDS
// with COUNTED vmcnt(4): iter t issues 4 loads for tile t+2, computes tile t,
// waits vmcnt(4) (t+1 landed, t+2 in flight across the barrier). 48 KB LDS.
// Compile-time epilogue:
//   EMODE 0: C = v (bf16/f32 per outbf, optional fast gelu)
//   EMODE 1: x4[perm(row)] = x_in[perm(row)] + v  ((b,n,t)->(b,t,n) permute)
//   EMODE 2: x4[row] += ada_gate * v; optional final output write
template<int EMODE>
__global__ __launch_bounds__(256, 3) void k_mgemm(
    const bf16* __restrict__ A, const bf16* __restrict__ Wt,
    const float* __restrict__ bias, void* __restrict__ Cout,
    int K, int N, int outbf, int act,
    float* __restrict__ x4, const float* __restrict__ ada, int part,
    const void* __restrict__ xin, void* __restrict__ outp,
    const int* __restrict__ flg)
{
    __shared__ short As[12288];   // 3 stages x (8 row-groups x 512) = 24 KB
    __shared__ short Bs[12288];   // 3 stages x (8 col-groups x 512) = 24 KB
    int tid = threadIdx.x;
    int lane = tid & 63, wave = tid >> 6;   // 4 waves
    int mq = wave >> 1, nq = wave & 1;      // 2M x 2N wave grid

    // bijective XCD-chunked swizzle
    int gx = gridDim.x;
    int nwg = gx * (int)gridDim.y;
    int orig = blockIdx.y * gx + blockIdx.x;
    int qq = nwg >> 3, rr = nwg & 7;
    int xcd = orig & 7, loc = orig >> 3;
    int wg = (xcd < rr ? xcd * (qq + 1) : rr * (qq + 1) + (xcd - rr) * qq) + loc;
    int bx = wg % gx, by = wg / gx;

    long row0 = (long)by << 7;   // 128-row tile
    long col0 = (long)bx << 7;   // 128-col tile
    int mi = lane & 15, q = lane >> 4;

    // staging: wave stages A row-groups {2w,2w+1} and B col-groups {2w,2w+1}
    const bf16* gA0 = A  + (row0 + (2 * wave) * 16 + mi) * K + q * 8;
    const bf16* gA1 = gA0 + 16 * K;
    const bf16* gB0 = Wt + (col0 + (2 * wave) * 16 + mi) * K + q * 8;
    const bf16* gB1 = gB0 + 16 * K;
    int dA0 = (2 * wave) * 512, dA1 = dA0 + 512;

    floatx4 acc[4][4] = {};
    int nt = K >> 5;                     // >= 3 for all our shapes

    // prologue: stage tiles 0 (stage 0) and 1 (stage 1); 8 loads in flight
    GLDS(gA0,      &As[dA0]);
    GLDS(gA1,      &As[dA1]);
    GLDS(gB0,      &Bs[dA0]);
    GLDS(gB1,      &Bs[dA1]);
    GLDS(gA0 + 32, &As[4096 + dA0]);
    GLDS(gA1 + 32, &As[4096 + dA1]);
    GLDS(gB0 + 32, &Bs[4096 + dA0]);
    GLDS(gB1 + 32, &Bs[4096 + dA1]);
    __builtin_amdgcn_sched_barrier(0);
    asm volatile("s_waitcnt vmcnt(4)" ::: "memory");   // tile 0 landed
    __builtin_amdgcn_sched_barrier(0);
    __builtin_amdgcn_s_barrier();
    __builtin_amdgcn_sched_barrier(0);

    int aRd = mq * 2048 + lane * 8;      // A frag: group mq*4+i at +i*512
    int bRd = nq * 2048 + lane * 8;      // B frag: group nq*4+j at +j*512
    int cs = 0;                          // stage holding tile t
    int si = 2;                          // stage for tile t+2

    for (int t = 0; t < nt; ++t) {
        if (t + 2 < nt) {                // issue tile t+2 (4 loads/wave)
            int o = si << 12;            // si*4096
            int kt2 = (t + 2) << 5;
            GLDS(gA0 + kt2, &As[o + dA0]);
            GLDS(gA1 + kt2, &As[o + dA1]);
            GLDS(gB0 + kt2, &Bs[o + dA0]);
            GLDS(gB1 + kt2, &Bs[o + dA1]);
        }
        // compute tile t from stage cs
        {
            int o = cs << 12;
            short8 af[4], bfr[4];
            #pragma unroll
            for (int i = 0; i < 4; ++i)
                af[i] = *(const short8*)&As[o + aRd + i * 512];
            #pragma unroll
            for (int j = 0; j < 4; ++j)
                bfr[j] = *(const short8*)&Bs[o + bRd + j * 512];
            #pragma unroll
            for (int i = 0; i < 4; ++i)
                #pragma unroll
                for (int j = 0; j < 4; ++j)
                    acc[i][j] = __builtin_amdgcn_mfma_f32_16x16x32_bf16(
                        af[i], bfr[j], acc[i][j], 0, 0, 0);
        }
        __builtin_amdgcn_sched_barrier(0);
        if (t + 2 < nt) asm volatile("s_waitcnt vmcnt(4)" ::: "memory"); // t+1 done, t+2 flying
        else            asm volatile("s_waitcnt vmcnt(0)" ::: "memory"); // tail drain
        __builtin_amdgcn_sched_barrier(0);
        if (t < nt - 1) {
            __builtin_amdgcn_s_barrier();
            __builtin_amdgcn_sched_barrier(0);
        }
        cs = (cs == 2) ? 0 : cs + 1;
        si = (si == 2) ? 0 : si + 1;
    }

    int lr = lane >> 4, lc = lane & 15;
    int fl = flg ? *flg : 0;
    float b4[4] = {0.f, 0.f, 0.f, 0.f};
    if (bias) {
        #pragma unroll
        for (int j = 0; j < 4; ++j) b4[j] = bias[(int)col0 + nq * 64 + j * 16 + lc];
    }
    #pragma unroll
    for (int i = 0; i < 4; ++i) {
        #pragma unroll
        for (int r = 0; r < 4; ++r) {
            long grow = row0 + mq * 64 + i * 16 + lr * 4 + r;
            #pragma unroll
            for (int j = 0; j < 4; ++j) {
                int col = (int)col0 + nq * 64 + j * 16 + lc;
                float v = acc[i][j][r] + b4[j];
                if (act) {
                    // gelu(tanh) == x * sigmoid(2 * 0.7978845608 * (x + 0.044715 x^3))
                    float u = v;
                    float tt = 1.5957691216057308f * (u + 0.044715f * u * u * u);
                    v = u / (1.f + __expf(-tt));
                }
                if constexpr (EMODE == 0) {
                    if (outbf) ((bf16*)Cout)[grow * N + col] = __float2bfloat16(v);
                    else       ((float*)Cout)[grow * N + col] = v;
                } else if constexpr (EMODE == 1) {
                    // grow is (b,n,t); x4/x rows are (b,t,n)
                    int bb = (int)(grow >> 12);
                    int nn = ((int)grow >> 4) & 255;
                    int tt2 = (int)grow & 15;
                    long rx = ((long)((bb << 4) + tt2) << 8) + nn;
                    long idx = rx * 1152 + col;
                    float xv = (fl == 0) ? b2f(((const bf16*)xin)[idx])
                                         : ((const float*)xin)[idx];
                    x4[idx] = xv + v;
                } else {
                    int bb = (int)(grow >> 12);
                    float g = ada[(bb * 6 + part) * 1152 + col];
                    long idx = grow * 1152 + col;
                    float nv = x4[idx] + g * v;
                    x4[idx] = nv;
                    if (outp) {
                        if (fl == 0) ((bf16*)outp)[idx] = __float2bfloat16(nv);
                        else         ((float*)outp)[idx] = nv;
                    }
                }
            }
        }
    }
}

// ---------------- LN (temporal), vectorized: 320 thr, 288 active x 4 cols ----------------
__global__ __launch_bounds__(320) void k_ln_t(
    const void* __restrict__ x, const void* __restrict__ w,
    const void* __restrict__ bb, bf16* __restrict__ out,
    const int* __restrict__ flg)
{
    __shared__ float rs[5], rss[5];
    int r = blockIdx.x;
    int n = r & 255;
    int bt = r >> 8;
    int b = bt >> 4, t = bt & 15;
    long orow = (long)((b << 8) + n) * 16 + t;
    int tid = threadIdx.x;
    int fl = *flg;
    float4 v4 = make_float4(0.f, 0.f, 0.f, 0.f);
    int c0 = tid << 2;
    if (tid < 288) {
        if (fl == 0) {
            ushort4 u = *(const ushort4*)((const unsigned short*)x + (long)r * 1152 + c0);
            bf16 h0, h1, h2, h3;
            *(unsigned short*)&h0 = u.x; *(unsigned short*)&h1 = u.y;
            *(unsigned short*)&h2 = u.z; *(unsigned short*)&h3 = u.w;
            v4 = make_float4(b2f(h0), b2f(h1), b2f(h2), b2f(h3));
        } else {
            v4 = *(const float4*)((const float*)x + (long)r * 1152 + c0);
        }
    }
    float s  = v4.x + v4.y + v4.z + v4.w;
    float ss = v4.x * v4.x + v4.y * v4.y + v4.z * v4.z + v4.w * v4.w;
    #pragma unroll
    for (int off = 32; off > 0; off >>= 1) {
        s  += __shfl_down(s, off);
        ss += __shfl_down(ss, off);
    }
    int wid = tid >> 6;
    if ((tid & 63) == 0) { rs[wid] = s; rss[wid] = ss; }
    __syncthreads();
    float S  = rs[0] + rs[1] + rs[2] + rs[3] + rs[4];
    float SS = rss[0] + rss[1] + rss[2] + rss[3] + rss[4];
    float mu = S * (1.f / 1152.f);
    float var = SS * (1.f / 1152.f) - mu * mu;
    float rstd = rsqrtf(var + 1e-5f);
    if (tid < 288) {
        ushort4 o4;
        float w0 = ldf(w, c0, fl),     w1 = ldf(w, c0 + 1, fl);
        float w2 = ldf(w, c0 + 2, fl), w3 = ldf(w, c0 + 3, fl);
        float bb0 = ldf(bb, c0, fl),     bb1 = ldf(bb, c0 + 1, fl);
        float bb2 = ldf(bb, c0 + 2, fl), bb3 = ldf(bb, c0 + 3, fl);
        o4.x = (unsigned short)f2bs((v4.x - mu) * rstd * w0 + bb0);
        o4.y = (unsigned short)f2bs((v4.y - mu) * rstd * w1 + bb1);
        o4.z = (unsigned short)f2bs((v4.z - mu) * rstd * w2 + bb2);
        o4.w = (unsigned short)f2bs((v4.w - mu) * rstd * w3 + bb3);
        *(ushort4*)((unsigned short*)out + orow * 1152 + c0) = o4;
    }
}

// ---------------- LN + adaLN modulation, vectorized ----------------
__global__ __launch_bounds__(320) void k_ln_mod(
    const float* __restrict__ x4, const float* __restrict__ ada,
    int psh, int psc, float eps, bf16* __restrict__ out)
{
    __shared__ float rs[5], rss[5];
    int r = blockIdx.x;
    int b = r >> 12;
    const float* xp = x4 + (long)r * 1152;
    int tid = threadIdx.x;
    int c0 = tid << 2;
    float4 v4 = make_float4(0.f, 0.f, 0.f, 0.f);
    if (tid < 288) v4 = *(const float4*)(xp + c0);
    float s  = v4.x + v4.y + v4.z + v4.w;
    float ss = v4.x * v4.x + v4.y * v4.y + v4.z * v4.z + v4.w * v4.w;
    #pragma unroll
    for (int off = 32; off > 0; off >>= 1) {
        s  += __shfl_down(s, off);
        ss += __shfl_down(ss, off);
    }
    int wid = tid >> 6;
    if ((tid & 63) == 0) { rs[wid] = s; rss[wid] = ss; }
    __syncthreads();
    float S  = rs[0] + rs[1] + rs[2] + rs[3] + rs[4];
    float SS = rss[0] + rss[1] + rss[2] + rss[3] + rss[4];
    float mu = S * (1.f / 1152.f);
    float var = SS * (1.f / 1152.f) - mu * mu;
    float rstd = rsqrtf(var + eps);
    if (tid < 288) {
        float4 sh4 = *(const float4*)(ada + (b * 6 + psh) * 1152 + c0);
        float4 sc4 = *(const float4*)(ada + (b * 6 + psc) * 1152 + c0);
        ushort4 o4;
        o4.x = (unsigned short)f2bs((v4.x - mu) * rstd * (1.f + sc4.x) + sh4.x);
        o4.y = (unsigned short)f2bs((v4.y - mu) * rstd * (1.f + sc4.y) + sh4.y);
        o4.z = (unsigned short)f2bs((v4.z - mu) * rstd * (1.f + sc4.z) + sh4.z);
        o4.w = (unsigned short)f2bs((v4.w - mu) * rstd * (1.f + sc4.w) + sh4.w);
        *(ushort4*)((unsigned short*)out + (long)r * 1152 + c0) = o4;
    }
}

// ---------------- temporal attention (conflict-free VALU) ----------------
__global__ __launch_bounds__(256) void k_attn_t(
    const bf16* __restrict__ qkv, const float* __restrict__ ekt,
    const float* __restrict__ evt, const float* __restrict__ ropeC,
    const float* __restrict__ ropeS, bf16* __restrict__ out)
{
    __shared__ float qs[16][73];
    __shared__ float ksT[72][33];
    __shared__ float vs[32][73];
    __shared__ float sc[16][33];
    int blk = blockIdx.x;
    int h = blk & 15;
    int bn = blk >> 4;
    int b = bn >> 8;
    int tid = threadIdx.x;
    long qbase = (long)bn * 16 * 3456 + h * 72;
    for (int idx = tid; idx < 16 * 72; idx += 256) {
        int i = idx / 72, d = idx - i * 72;
        long p0 = qbase + (long)i * 3456;
        float v  = b2f(qkv[p0 + d]);
        float v2 = b2f(qkv[p0 + (d ^ 1)]);
        float cs = ropeC[idx], sn = ropeS[idx];
        float rv = (d & 1) ? (v * cs + v2 * sn) : (v * cs - v2 * sn);
        qs[i][d] = rv * SCALE_;
    }
    for (int idx = tid; idx < 32 * 72; idx += 256) {
        int j = idx / 72, d = idx - j * 72;
        float kv, kv2, vv; int pi;
        if (j < 16) {
            long base = (long)(b * 16 + j) * 1152 + h * 72;
            kv  = ekt[base + d];
            kv2 = ekt[base + (d ^ 1)];
            vv  = evt[base + d];
            pi = j;
        } else {
            int jj = j - 16;
            long base = qbase + (long)jj * 3456;
            kv  = b2f(qkv[base + 1152 + d]);
            kv2 = b2f(qkv[base + 1152 + (d ^ 1)]);
            vv  = b2f(qkv[base + 2304 + d]);
            pi = jj;
        }
        float cs = ropeC[pi * 72 + d], sn = ropeS[pi * 72 + d];
        ksT[d][j] = (d & 1) ? (kv * cs + kv2 * sn) : (kv * cs - kv2 * sn);
        vs[j][d] = vv;
    }
    __syncthreads();
    for (int e = tid; e < 512; e += 256) {
        int i = e >> 5, j = e & 31;
        float s = 0.f;
        for (int d = 0; d < 72; ++d) s += qs[i][d] * ksT[d][j];
        sc[i][j] = s;
    }
    __syncthreads();
    if (tid < 16) {
        float m = -1e30f;
        for (int j = 0; j < 32; ++j) m = fmaxf(m, sc[tid][j]);
        float l = 0.f;
        for (int j = 0; j < 32; ++j) { float p = expf(sc[tid][j] - m); sc[tid][j] = p; l += p; }
        float inv = 1.f / l;
        for (int j = 0; j < 32; ++j) sc[tid][j] *= inv;
    }
    __syncthreads();
    for (int idx = tid; idx < 16 * 72; idx += 256) {
        int i = idx / 72, d = idx - i * 72;
        float o = 0.f;
        for (int j = 0; j < 32; ++j) o += sc[i][j] * vs[j][d];
        out[((long)bn * 16 + i) * 1152 + h * 72 + d] = __float2bfloat16(o);
    }
}

// ---------------- spatial attention: MFMA flash ----------------
__global__ __launch_bounds__(256) void k_attn_s(
    const bf16* __restrict__ qkv, const bf16* __restrict__ eksb,
    const bf16* __restrict__ evsb, bf16* __restrict__ out)
{
    __shared__ short vT[5120];       // V^T frag-linear: (dn*2+ks)*512 + fl*8
    __shared__ short pl[4][1024];    // per-wave P frags: ks*512 + lane*8
    int tid = threadIdx.x;
    int lane = tid & 63, wave = tid >> 6;
    int blk = blockIdx.x;
    int ic = blk & 3;
    int bth = blk >> 2;
    int h = bth & 15;
    int bt = bth >> 4;
    int col = lane & 15, q = lane >> 4;
    int hoff = h * 72;
    long qkvbase = (long)bt * 256 * 3456;
    long ctxbase = (long)bt * 1152 + hoff;

    int qrow = ic * 64 + wave * 16 + col;
    const bf16* qptr = qkv + qkvbase + (long)qrow * 3456 + hoff;
    short8 qf[3];
    #pragma unroll
    for (int ks = 0; ks < 3; ++ks) {
        int k0 = ks * 32 + q * 8;
        if (k0 + 8 <= 72) qf[ks] = *(const short8*)(qptr + k0);
        else { short8 z = {0,0,0,0,0,0,0,0}; qf[ks] = z; }
    }

    floatx4 o[5] = {};
    float m_i[4], l_i[4];
    #pragma unroll
    for (int r = 0; r < 4; ++r) { m_i[r] = -1e30f; l_i[r] = 0.f; }

    for (int kc = 0; kc < 320; kc += 64) {
        for (int fi = tid; fi < 640; fi += 256) {
            int blkid = fi >> 6, fl2 = fi & 63;
            int dn = blkid >> 1, ks = blkid & 1;
            int d = dn * 16 + (fl2 & 15);
            int kq = fl2 >> 4;
            short8 v;
            #pragma unroll
            for (int j = 0; j < 8; ++j) {
                int gk = kc + ks * 32 + kq * 8 + j;
                short sv = 0;
                if (d < 72 && gk <= 256) {
                    if (gk == 0) sv = *(const short*)(eksb ? &evsb[ctxbase + d] : nullptr);
                    else sv = *(const short*)&qkv[qkvbase + (long)(gk - 1) * 3456 + 2304 + hoff + d];
                }
                v[j] = sv;
            }
            *(short8*)&vT[blkid * 512 + fl2 * 8] = v;
        }
        __syncthreads();

        floatx4 sacc[4] = {};
        #pragma unroll
        for (int nt = 0; nt < 4; ++nt) {
            int key = kc + nt * 16 + col;
            #pragma unroll
            for (int ks = 0; ks < 3; ++ks) {
                int k0 = ks * 32 + q * 8;
                short8 kf = {0,0,0,0,0,0,0,0};
                if (key <= 256 && k0 + 8 <= 72) {
                    if (key == 0) kf = *(const short8*)(eksb + ctxbase + k0);
                    else kf = *(const short8*)(qkv + qkvbase + (long)(key - 1) * 3456 + 1152 + hoff + k0);
                }
                sacc[nt] = __builtin_amdgcn_mfma_f32_16x16x32_bf16(qf[ks], kf, sacc[nt], 0, 0, 0);
            }
        }

        float p[4][4];
        #pragma unroll
        for (int r = 0; r < 4; ++r) {
            float mv = -1e30f;
            #pragma unroll
            for (int nt = 0; nt < 4; ++nt) {
                int key = kc + nt * 16 + col;
                float s = (key <= 256) ? sacc[nt][r] * SCALE_ : -1e30f;
                p[nt][r] = s;
                mv = fmaxf(mv, s);
            }
            #pragma unroll
            for (int xm = 1; xm < 16; xm <<= 1) mv = fmaxf(mv, __shfl_xor(mv, xm));
            float mn = fmaxf(m_i[r], mv);
            float alpha = expf(m_i[r] - mn);
            m_i[r] = mn;
            float rsum = 0.f;
            #pragma unroll
            for (int nt = 0; nt < 4; ++nt) {
                float e = expf(p[nt][r] - mn);
                p[nt][r] = e;
                rsum += e;
            }
            #pragma unroll
            for (int xm = 1; xm < 16; xm <<= 1) rsum += __shfl_xor(rsum, xm);
            l_i[r] = l_i[r] * alpha + rsum;
            #pragma unroll
            for (int dn = 0; dn < 5; ++dn) o[dn][r] *= alpha;
        }

        #pragma unroll
        for (int nt = 0; nt < 4; ++nt) {
            int kl = nt * 16 + col;
            int ks2 = kl >> 5, q2 = (kl >> 3) & 3, j = kl & 7;
            #pragma unroll
            for (int r = 0; r < 4; ++r) {
                int mrow = q * 4 + r;
                pl[wave][ks2 * 512 + q2 * 128 + mrow * 8 + j] = f2bs(p[nt][r]);
            }
        }
        __syncthreads();

        #pragma unroll
        for (int ks = 0; ks < 2; ++ks) {
            short8 pf = *(const short8*)&pl[wave][ks * 512 + lane * 8];
            #pragma unroll
            for (int dn = 0; dn < 5; ++dn) {
                short8 vf = *(const short8*)&vT[(dn * 2 + ks) * 512 + lane * 8];
                o[dn] = __builtin_amdgcn_mfma_f32_16x16x32_bf16(pf, vf, o[dn], 0, 0, 0);
            }
        }
        __syncthreads();
    }

    int orow0 = ic * 64 + wave * 16;
    #pragma unroll
    for (int dn = 0; dn < 5; ++dn) {
        int d = dn * 16 + col;
        if (d >= 72) continue;
        #pragma unroll
        for (int r = 0; r < 4; ++r) {
            int mrow = q * 4 + r;
            float val = o[dn][r] / l_i[r];
            out[((long)bt * 256 + orow0 + mrow) * 1152 + hoff + d] = __float2bfloat16(val);
        }
    }
}

extern "C" void kernel_launch(void* const* d_in, const int* in_sizes, int n_in,
                              void* d_out, int out_size, void* d_ws, size_t ws_size,
                              hipStream_t stream)
{
    const void* x      = d_in[0];
    const void* c4t    = d_in[1];
    const void* c      = d_in[2];
    const void* W_ada  = d_in[3];
    const void* b_ada  = d_in[4];
    const void* tn_w   = d_in[5];
    const void* tn_b   = d_in[6];
    const void* t_qkv  = d_in[7];
    const void* t_k    = d_in[8];
    const void* t_v    = d_in[9];
    const void* t_outw = d_in[10];
    const void* t_fcw  = d_in[11];
    const void* t_fcb  = d_in[12];
    const void* s_qkv  = d_in[13];
    const void* s_k    = d_in[14];
    const void* s_v    = d_in[15];
    const void* s_outw = d_in[16];
    const void* mlp_w1 = d_in[17];
    const void* mlp_b1 = d_in[18];
    const void* mlp_w2 = d_in[19];
    const void* mlp_b2 = d_in[20];
    const int*  f      = (const int*)d_in[21];

    float* ws    = (float*)d_ws;
    float* x4    = ws;                        //  9,437,184 f32
    float* buf2  = x4 + 9437184;              //  9,437,184 f32 (reused: wc_t, t_out_b)
    bf16*  wc_t  = (bf16*)buf2;               //  1,327,104 bf16 combined (t_out@t_fc)^T
    bf16*  t_out_b = wc_t + 1327104;          //  1,327,104 bf16 straight copy of t_out
    float* reg1f = buf2 + 9437184;            // 18,874,368 f32-slots
    bf16*  qkvb  = (bf16*)reg1f;
    bf16*  hbf   = (bf16*)reg1f;
    float* abfAf = reg1f + 18874368;          //  4,718,592 f32-slots
    bf16*  abfA  = (bf16*)abfAf;
    float* abfBf = abfAf + 4718592;           //  4,718,592 f32-slots
    bf16*  abfB  = (bf16*)abfBf;
    float* wtf   = abfBf + 4718592;           // 11,280,384 f32-slots
    bf16*  wt    = (bf16*)wtf;
    bf16* t_qkv_t = wt;
    bf16* s_qkv_t = t_qkv_t + 3981312;
    bf16* t_out_t = s_qkv_t + 3981312;
    bf16* t_fc_t  = t_out_t + 1327104;
    bf16* s_out_t = t_fc_t  + 1327104;
    bf16* w1_t    = s_out_t + 1327104;
    bf16* w2_t    = w1_t    + 5308416;
    float* small  = wtf + 11280384;
    float* ada   = small;                      // 13,824
    float* cf32  = ada  + 13824;               // 36,864
    float* ekt   = cf32 + 36864;
    float* evt   = ekt  + 36864;
    float* eks   = evt  + 36864;
    float* evs   = eks  + 36864;
    bf16*  eksb  = (bf16*)(evs + 36864);       // 36,864 bf16
    bf16*  evsb  = eksb + 36864;               // 36,864 bf16
    float* sc4   = (float*)(evsb + 36864);     // 2,304
    float* fcb_f = sc4  + 2304;
    float* b1_f  = fcb_f + 1152;
    float* b2_f  = b1_f  + 4608;
    float* ropeC = b2_f + 1152;
    float* ropeS = ropeC + 1152;
    int*   flg   = (int*)(ropeS + 1152);

    k_detect<<<1, 64, 0, stream>>>(x, flg);
    k_setup<<<185, 256, 0, stream>>>(c4t, c, t_fcb, mlp_b1, mlp_b2, f,
                                     sc4, cf32, fcb_f, b1_f, b2_f, ropeC, ropeS, flg);

    // ---- modulation + context projections (z>=2 write bf16 directly) ----
    k_gemm<<<dim3(108, 1), 256, 0, stream>>>(sc4, W_ada, b_ada, ada, 2, 1152, 6912, flg);
    k_gemm4<<<dim3(18, 4), 256, 0, stream>>>(cf32, t_k, t_v, s_k, s_v, ekt, eksb, flg);

    // ---- weight transpose+convert ----
    k_wt2<<<dim3(108, 36, 2), 256, 0, stream>>>(t_qkv, s_qkv, t_qkv_t, flg);
    k_wt3<<<dim3(36, 36, 3), 256, 0, stream>>>(t_outw, t_fcw, s_outw, t_out_t, flg);
    k_wt<<<dim3(144, 36), 256, 0, stream>>>(mlp_w1, w1_t, 1152, 4608, flg);
    k_wt<<<dim3(36, 144), 256, 0, stream>>>(mlp_w2, w2_t, 4608, 1152, flg);

    // ---- weight combine: Wc^T[c][k] = t_fc_t[c,:] . t_out_b[k,:]  (Wc = t_out@t_fc) ----
    k_cvtf<<<5184, 256, 0, stream>>>(t_outw, t_out_b, 1327104, flg);
    k_mgemm<0><<<dim3(9, 9), 256, 0, stream>>>(t_fc_t, t_out_b, nullptr, wc_t, 1152, 1152, 1, 0,
                                               nullptr, nullptr, 0, nullptr, nullptr, flg);

    // ---- temporal attention ----
    k_ln_t<<<8192, 320, 0, stream>>>(x, tn_w, tn_b, abfA, flg);
    k_mgemm<0><<<dim3(27, 64), 256, 0, stream>>>(abfA, t_qkv_t, nullptr, qkvb, 1152, 3456, 1, 0,
                                                 nullptr, nullptr, 0, nullptr, nullptr, flg);
    k_attn_t<<<8192, 256, 0, stream>>>(qkvb, ekt, evt, ropeC, ropeS, abfB);
    // combined (t_out . t_fc) with residual add + (b,n,t)->(b,t,n) permute
    k_mgemm<1><<<dim3(9, 64), 256, 0, stream>>>(abfB, wc_t, fcb_f, nullptr, 1152, 1152, 0, 0,
                                                x4, nullptr, 0, x, nullptr, flg);

    // ---- spatial attention ----
    k_ln_mod<<<8192, 320, 0, stream>>>(x4, ada, 0, 1, 1e-6f, abfA);
    k_mgemm<0><<<dim3(27, 64), 256, 0, stream>>>(abfA, s_qkv_t, nullptr, qkvb, 1152, 3456, 1, 0,
                                                 nullptr, nullptr, 0, nullptr, nullptr, flg);
    k_attn_s<<<2048, 256, 0, stream>>>(qkvb, eksb, evsb, abfB);
    // s_out fused with gated accumulate (part 2)
    k_mgemm<2><<<dim3(9, 64), 256, 0, stream>>>(abfB, s_out_t, nullptr, nullptr, 1152, 1152, 0, 0,
                                                x4, ada, 2, nullptr, nullptr, flg);

    // ---- MLP ----
    k_ln_mod<<<8192, 320, 0, stream>>>(x4, ada, 3, 4, 1e-6f, abfA);
    k_mgemm<0><<<dim3(36, 64), 256, 0, stream>>>(abfA, w1_t, b1_f, hbf, 1152, 4608, 1, 1,
                                                 nullptr, nullptr, 0, nullptr, nullptr, flg);
    // w2 fused with gated accumulate (part 5) + final output emit
    k_mgemm<2><<<dim3(9, 64), 256, 0, stream>>>(hbf, w2_t, b2_f, nullptr, 4608, 1152, 0, 0,
                                                x4, ada, 5, nullptr, d_out, flg);
}